// Round 2
// baseline (217.849 us; speedup 1.0000x reference)
//
#include <hip/hip_runtime.h>

typedef __bf16 bf16x8 __attribute__((ext_vector_type(8)));
typedef float  f32x4  __attribute__((ext_vector_type(4)));

// Sizes: B=64, C=128, ORI=6, HW=784, NB=4, BS=32
// xh strides (floats): b:1204224, c:9408, ori:1568, hw:2, ri:1

static __device__ __forceinline__ unsigned short bf16bits(float f) {
  __bf16 h = (__bf16)f; return __builtin_bit_cast(unsigned short, h);
}
static __device__ __forceinline__ unsigned int pack2(float a, float b) {
  return (unsigned int)bf16bits(a) | ((unsigned int)bf16bits(b) << 16);
}

// ---------------- weight prep: combined real matrix, transposed [n][k], bf16,
// written as the PRE-SWIZZLED LDS image so the main kernel does a linear copy.
__global__ void prep_weights(const float* __restrict__ w1, const float* __restrict__ w2,
                             unsigned short* __restrict__ wg) {
  const int e = blockIdx.x * 256 + threadIdx.x;      // 0..32767
  const int nb    = e >> 13;
  const int layer = (e >> 12) & 1;
  const int n = (e >> 6) & 63;
  const int k = e & 63;
  const float* w = layer ? w2 : w1;
  const int kk = k & 31, nn = n & 31;
  float v;
  if (n < 32) {
    v = (k < 32) ?  w[((0 * 4 + nb) * 32 + kk) * 32 + nn]
                 : -w[((1 * 4 + nb) * 32 + kk) * 32 + nn];
  } else {
    v = (k < 32) ?  w[((1 * 4 + nb) * 32 + kk) * 32 + nn]
                 :  w[((0 * 4 + nb) * 32 + kk) * 32 + nn];
  }
  // swizzled position: group g=k>>3 -> g ^ ((n>>1)&7)
  const int pos = nb * 8192 + layer * 4096 + n * 64 + (((k >> 3) ^ ((n >> 1) & 7)) * 8) + (k & 7);
  wg[pos] = bf16bits(v);
}

// ---------------- fused main kernel ----------------
// grid = 1568: (bi&3)==3 -> lowpass stream block (392 of them);
// else xh block idx = (bi>>2)*3+(bi&3) in [0,1176): (ori,nb, group of 4 tiles of 256 pos)
__global__ __launch_bounds__(256, 3)
void fused_kernel(const float* __restrict__ xh, const unsigned short* __restrict__ wg,
                  const float* __restrict__ b1, const float* __restrict__ b2,
                  const float* __restrict__ xl, const float* __restrict__ wll,
                  float* __restrict__ out) {
  __shared__ __align__(16) unsigned short Xs[256 * 64];   // X tile -> H tile (bf16), 32KB
  __shared__ __align__(16) unsigned short Ws[2 * 64 * 64];// 16KB
  __shared__ __align__(16) float Bs[128];

  const int t = threadIdx.x;
  const int bi = blockIdx.x;

  if ((bi & 3) == 3) {                    // ---- lowpass path ----
    const int llb = bi >> 2;              // 0..391, 4096 float4 each
    const float4* xi4 = reinterpret_cast<const float4*>(xl);
    const float4* w4  = reinterpret_cast<const float4*>(wll);
    float4* o4 = reinterpret_cast<float4*>(out);
#pragma unroll
    for (int j = 0; j < 16; ++j) {
      const int i = llb * 4096 + j * 256 + t;
      const float4 x = xi4[i];
      const float4 w = w4[i % 25088];
      float4 r; r.x = x.x * w.x; r.y = x.y * w.y; r.z = x.z * w.z; r.w = x.w * w.w;
      o4[i] = r;
    }
    return;
  }

  const int xi = (bi >> 2) * 3 + (bi & 3);   // 0..1175
  const int tb  = xi % 49;
  const int snb = xi / 49;
  const int ori = snb >> 2;
  const int nb  = snb & 3;
  const int p00 = tb << 10;                  // 4 tiles * 256 positions

  // biases -> LDS
  if (t < 128) {
    const int layer = t >> 6, n = t & 63;
    const float* bsrc = layer ? b2 : b1;
    Bs[t] = bsrc[((n >> 5) * 4 + nb) * 32 + (n & 31)];
  }
  // weights -> LDS (linear copy of pre-swizzled image)
  {
    const uint4* src = reinterpret_cast<const uint4*>(wg + nb * 8192);
    uint4* dst = reinterpret_cast<uint4*>(Ws);
#pragma unroll
    for (int it = 0; it < 4; ++it) dst[it * 256 + t] = src[it * 256 + t];
  }

  const int lane = t & 63;
  const int wv = t >> 6;
  const int lr = lane & 15;
  const int lg = lane >> 4;
  const float* xb = xh + (size_t)(nb * 32) * 9408 + ori * 1568;
  float* ob = out + 6422528 + (size_t)(nb * 32) * 9408 + ori * 1568;
  char* XB = reinterpret_cast<char*>(Xs);
  const char* WB = reinterpret_cast<const char*>(Ws);

  f32x4 R[16];                               // raw fp32 prefetch regs (64 VGPR)

  auto issue_loads = [&](int p0) {
#pragma unroll
    for (int j = 0; j < 8; ++j) {
      const int idx = j * 256 + t;
      const int c = (idx >> 7) * 2;
      const int p = (idx & 127) * 2;
      const int P = p0 + p;
      const int bb = P / 784;
      const int hw = P - bb * 784;
      const float* s = xb + (size_t)bb * 1204224 + c * 9408 + hw * 2;
      R[2 * j]     = *reinterpret_cast<const f32x4*>(s);
      R[2 * j + 1] = *reinterpret_cast<const f32x4*>(s + 9408);
    }
  };
  auto stage_writes = [&]() {
#pragma unroll
    for (int j = 0; j < 8; ++j) {
      const int idx = j * 256 + t;
      const int c = (idx >> 7) * 2;
      const int p = (idx & 127) * 2;
      const int g0 = c >> 3;
      const int off = (c & 7) * 2;
      const int s0 = (p >> 1) & 7;
      const f32x4 vA = R[2 * j], vB = R[2 * j + 1];
      *reinterpret_cast<unsigned int*>(XB + p * 128 + ((g0 ^ s0) * 16) + off)             = pack2(vA[0], vB[0]);
      *reinterpret_cast<unsigned int*>(XB + p * 128 + (((g0 + 4) ^ s0) * 16) + off)       = pack2(vA[1], vB[1]);
      *reinterpret_cast<unsigned int*>(XB + (p + 1) * 128 + ((g0 ^ s0) * 16) + off)       = pack2(vA[2], vB[2]);
      *reinterpret_cast<unsigned int*>(XB + (p + 1) * 128 + (((g0 + 4) ^ s0) * 16) + off) = pack2(vA[3], vB[3]);
    }
  };

  // prologue: X(tile0) staged; X(tile1) loads in flight after the barrier
  issue_loads(p00);
  stage_writes();
  __syncthreads();
  issue_loads(p00 + 256);

#pragma unroll
  for (int tt = 0; tt < 4; ++tt) {
    // ---- layer 1: D1[n][p] = W1t * X^T ----
    f32x4 acc[4][4];
#pragma unroll
    for (int mi = 0; mi < 4; ++mi)
#pragma unroll
      for (int ni = 0; ni < 4; ++ni)
        acc[mi][ni] = (f32x4){0.f, 0.f, 0.f, 0.f};

#pragma unroll
    for (int ks = 0; ks < 2; ++ks) {
      bf16x8 wf[4], xf[4];
#pragma unroll
      for (int mi = 0; mi < 4; ++mi) {
        const int n = mi * 16 + lr;
        wf[mi] = *reinterpret_cast<const bf16x8*>(WB + n * 128 + (((ks * 4 + lg) ^ ((n >> 1) & 7)) * 16));
      }
#pragma unroll
      for (int ni = 0; ni < 4; ++ni) {
        const int p = wv * 64 + ni * 16 + lr;
        xf[ni] = *reinterpret_cast<const bf16x8*>(XB + p * 128 + (((ks * 4 + lg) ^ ((p >> 1) & 7)) * 16));
      }
#pragma unroll
      for (int mi = 0; mi < 4; ++mi)
#pragma unroll
        for (int ni = 0; ni < 4; ++ni)
          acc[mi][ni] = __builtin_amdgcn_mfma_f32_16x16x32_bf16(wf[mi], xf[ni], acc[mi][ni], 0, 0, 0);
    }

    // ---- ep1: H = relu(D1 + b1) -> back into Xs (wave-private rows, no barrier) ----
#pragma unroll
    for (int mi = 0; mi < 4; ++mi) {
      const f32x4 bv = *reinterpret_cast<const f32x4*>(&Bs[mi * 16 + lg * 4]);
      const int gH = mi * 2 + (lg >> 1);
      const int offH = (lg & 1) * 8;
#pragma unroll
      for (int ni = 0; ni < 4; ++ni) {
        const int p = wv * 64 + ni * 16 + lr;
        const float h0 = fmaxf(acc[mi][ni][0] + bv[0], 0.f);
        const float h1 = fmaxf(acc[mi][ni][1] + bv[1], 0.f);
        const float h2 = fmaxf(acc[mi][ni][2] + bv[2], 0.f);
        const float h3 = fmaxf(acc[mi][ni][3] + bv[3], 0.f);
        uint2 u; u.x = pack2(h0, h1); u.y = pack2(h2, h3);
        *reinterpret_cast<uint2*>(XB + p * 128 + ((gH ^ ((p >> 1) & 7)) * 16) + offH) = u;
      }
    }

    // ---- layer 2: D2[n][p] = W2t * H^T (wave-private rows) ----
    f32x4 acc2[4][4];
#pragma unroll
    for (int mi = 0; mi < 4; ++mi)
#pragma unroll
      for (int ni = 0; ni < 4; ++ni)
        acc2[mi][ni] = (f32x4){0.f, 0.f, 0.f, 0.f};

#pragma unroll
    for (int ks = 0; ks < 2; ++ks) {
      bf16x8 wf[4], hf[4];
#pragma unroll
      for (int mi = 0; mi < 4; ++mi) {
        const int n = mi * 16 + lr;
        wf[mi] = *reinterpret_cast<const bf16x8*>(WB + 8192 + n * 128 + (((ks * 4 + lg) ^ ((n >> 1) & 7)) * 16));
      }
#pragma unroll
      for (int ni = 0; ni < 4; ++ni) {
        const int p = wv * 64 + ni * 16 + lr;
        hf[ni] = *reinterpret_cast<const bf16x8*>(XB + p * 128 + (((ks * 4 + lg) ^ ((p >> 1) & 7)) * 16));
      }
#pragma unroll
      for (int mi = 0; mi < 4; ++mi)
#pragma unroll
        for (int ni = 0; ni < 4; ++ni)
          acc2[mi][ni] = __builtin_amdgcn_mfma_f32_16x16x32_bf16(wf[mi], hf[ni], acc2[mi][ni], 0, 0, 0);
    }

    // ---- pipeline: restage Xs with next tile, then issue tile tt+2 loads ----
    if (tt < 3) {
      __syncthreads();                       // all waves done reading Xs (loads/stores long landed)
      stage_writes();                        // X(tt+1) -> Xs
      __syncthreads();                       // LDS writes visible (lgkm only, cheap)
      if (tt < 2) issue_loads(p00 + (tt + 2) * 256);  // in flight across ep2 + next compute
    }

    // ---- ep2: out = D2 + b2, interleaved (re,im) float2 stores ----
    {
      const int p0 = p00 + tt * 256;
#pragma unroll
      for (int ni = 0; ni < 4; ++ni) {
        const int p = wv * 64 + ni * 16 + lr;
        const int P = p0 + p;
        const int bb = P / 784;
        const int hw = P - bb * 784;
        float* obase = ob + (size_t)bb * 1204224 + hw * 2;
#pragma unroll
        for (int mi = 0; mi < 2; ++mi) {
          const f32x4 bre = *reinterpret_cast<const f32x4*>(&Bs[64 + mi * 16 + lg * 4]);
          const f32x4 bim = *reinterpret_cast<const f32x4*>(&Bs[64 + (mi + 2) * 16 + lg * 4]);
#pragma unroll
          for (int j = 0; j < 4; ++j) {
            const int c = mi * 16 + lg * 4 + j;
            float2 v;
            v.x = acc2[mi][ni][j] + bre[j];
            v.y = acc2[mi + 2][ni][j] + bim[j];
            *reinterpret_cast<float2*>(obase + (size_t)c * 9408) = v;
          }
        }
      }
    }
  }
}

extern "C" void kernel_launch(void* const* d_in, const int* in_sizes, int n_in,
                              void* d_out, int out_size, void* d_ws, size_t ws_size,
                              hipStream_t stream) {
  (void)in_sizes; (void)n_in; (void)out_size; (void)ws_size;
  const float* xl  = (const float*)d_in[0];
  const float* xh  = (const float*)d_in[1];
  const float* wll = (const float*)d_in[2];
  const float* w1  = (const float*)d_in[3];
  const float* w2  = (const float*)d_in[4];
  const float* b1  = (const float*)d_in[5];
  const float* b2  = (const float*)d_in[6];
  float* out = (float*)d_out;
  unsigned short* wg = (unsigned short*)d_ws;   // 65536 bytes used

  prep_weights<<<128, 256, 0, stream>>>(w1, w2, wg);
  fused_kernel<<<1568, 256, 0, stream>>>(xh, wg, b1, b2, xl, wll, out);
}

// Round 3
// 151.436 us; speedup vs baseline: 1.4386x; 1.4386x over previous
//
#include <hip/hip_runtime.h>

typedef __bf16 bf16x8 __attribute__((ext_vector_type(8)));
typedef float  f32x4  __attribute__((ext_vector_type(4)));

// Sizes: B=64, C=128, ORI=6, HW=784, NB=4, BS=32
// xh strides (floats): b:1204224, c:9408, ori:1568, hw:2, ri:1

static __device__ __forceinline__ unsigned short bf16bits(float f) {
  __bf16 h = (__bf16)f; return __builtin_bit_cast(unsigned short, h);
}
static __device__ __forceinline__ unsigned int pack2(float a, float b) {
  return (unsigned int)bf16bits(a) | ((unsigned int)bf16bits(b) << 16);
}

// ---------------- weight prep: combined real matrix, transposed [n][k], bf16,
// written as the PRE-SWIZZLED LDS image so the main kernel does a linear copy.
__global__ void prep_weights(const float* __restrict__ w1, const float* __restrict__ w2,
                             unsigned short* __restrict__ wg) {
  const int e = blockIdx.x * 256 + threadIdx.x;      // 0..32767
  const int nb    = e >> 13;
  const int layer = (e >> 12) & 1;
  const int n = (e >> 6) & 63;
  const int k = e & 63;
  const float* w = layer ? w2 : w1;
  const int kk = k & 31, nn = n & 31;
  float v;
  if (n < 32) {
    v = (k < 32) ?  w[((0 * 4 + nb) * 32 + kk) * 32 + nn]
                 : -w[((1 * 4 + nb) * 32 + kk) * 32 + nn];
  } else {
    v = (k < 32) ?  w[((1 * 4 + nb) * 32 + kk) * 32 + nn]
                 :  w[((0 * 4 + nb) * 32 + kk) * 32 + nn];
  }
  // swizzled position: group g=k>>3 -> g ^ ((n>>1)&7)
  const int pos = nb * 8192 + layer * 4096 + n * 64 + (((k >> 3) ^ ((n >> 1) & 7)) * 8) + (k & 7);
  wg[pos] = bf16bits(v);
}

// ---------------- fused main kernel ----------------
// grid = 6272: (bi&3)==3 -> lowpass block (1568); else xh block (4704):
// xi = (bi>>2)*3+(bi&3); (ori, nb, one 256-position tile)
__global__ __launch_bounds__(256, 3)
void fused_kernel(const float* __restrict__ xh, const unsigned short* __restrict__ wg,
                  const float* __restrict__ b1, const float* __restrict__ b2,
                  const float* __restrict__ xl, const float* __restrict__ wll,
                  float* __restrict__ out) {
  __shared__ __align__(16) unsigned short Xs[256 * 64];   // X tile -> H tile (bf16), 32KB
  __shared__ __align__(16) unsigned short Ws[2 * 64 * 64];// 16KB
  __shared__ __align__(16) float Bs[128];

  const int t = threadIdx.x;
  const int bi = blockIdx.x;

  if ((bi & 3) == 3) {                    // ---- lowpass path: xl_out = xl * w_ll ----
    const int llb = bi >> 2;              // 0..1567, 1024 float4 each
    const float4* xi4 = reinterpret_cast<const float4*>(xl);
    const float4* w4  = reinterpret_cast<const float4*>(wll);
    float4* o4 = reinterpret_cast<float4*>(out);
#pragma unroll
    for (int j = 0; j < 4; ++j) {
      const int i = llb * 1024 + j * 256 + t;
      const float4 x = xi4[i];
      const float4 w = w4[i % 25088];
      float4 r; r.x = x.x * w.x; r.y = x.y * w.y; r.z = x.z * w.z; r.w = x.w * w.w;
      o4[i] = r;
    }
    return;
  }

  const int xi = (bi >> 2) * 3 + (bi & 3);   // 0..4703
  const int mt  = xi % 196;
  const int snb = xi / 196;
  const int ori = snb >> 2;
  const int nb  = snb & 3;
  const int p0 = mt << 8;

  // biases -> LDS
  if (t < 128) {
    const int layer = t >> 6, n = t & 63;
    const float* bsrc = layer ? b2 : b1;
    Bs[t] = bsrc[((n >> 5) * 4 + nb) * 32 + (n & 31)];
  }
  // weights -> LDS (linear copy of pre-swizzled image)
  {
    const uint4* src = reinterpret_cast<const uint4*>(wg + nb * 8192);
    uint4* dst = reinterpret_cast<uint4*>(Ws);
#pragma unroll
    for (int it = 0; it < 4; ++it) dst[it * 256 + t] = src[it * 256 + t];
  }

  char* XB = reinterpret_cast<char*>(Xs);
  const char* WB = reinterpret_cast<const char*>(Ws);
  const float* xb = xh + (size_t)(nb * 32) * 9408 + ori * 1568;
  float* ob = out + 6422528 + (size_t)(nb * 32) * 9408 + ori * 1568;

  // ---- stage X tile, conflict-free mapping:
  // 16-lane groups -> positions, 4 groups/wave -> channel pairs
  {
    const int lr16 = t & 15;
    const int cg   = (t >> 4) & 3;
    const int w    = t >> 6;
#pragma unroll
    for (int j = 0; j < 8; ++j) {
      const int c = 2 * cg + 8 * (j >> 1);           // even channel of pair
      const int p = 2 * lr16 + 32 * (w * 2 + (j & 1)); // even local position
      const int P = p0 + p;
      const int bb = P / 784;
      const int hw = P - bb * 784;
      const float* s = xb + (size_t)bb * 1204224 + c * 9408 + hw * 2;
      const f32x4 vA = *reinterpret_cast<const f32x4*>(s);          // ch c : re,im,re,im
      const f32x4 vB = *reinterpret_cast<const f32x4*>(s + 9408);   // ch c+1
      const int g0 = c >> 3;
      const int off = (c & 7) * 2;
      const int s0 = (p >> 1) & 7;
      *reinterpret_cast<unsigned int*>(XB + p * 128 + ((g0 ^ s0) * 16) + off)             = pack2(vA[0], vB[0]);
      *reinterpret_cast<unsigned int*>(XB + p * 128 + (((g0 + 4) ^ s0) * 16) + off)       = pack2(vA[1], vB[1]);
      *reinterpret_cast<unsigned int*>(XB + (p + 1) * 128 + ((g0 ^ s0) * 16) + off)       = pack2(vA[2], vB[2]);
      *reinterpret_cast<unsigned int*>(XB + (p + 1) * 128 + (((g0 + 4) ^ s0) * 16) + off) = pack2(vA[3], vB[3]);
    }
  }
  __syncthreads();

  const int lane = t & 63;
  const int wv = t >> 6;
  const int lr = lane & 15;
  const int lg = lane >> 4;

  // ---- layer 1: D1[n][p] = W1t * X^T ----
  f32x4 acc[4][4];
#pragma unroll
  for (int mi = 0; mi < 4; ++mi)
#pragma unroll
    for (int ni = 0; ni < 4; ++ni)
      acc[mi][ni] = (f32x4){0.f, 0.f, 0.f, 0.f};

#pragma unroll
  for (int ks = 0; ks < 2; ++ks) {
    bf16x8 wf[4], xf[4];
#pragma unroll
    for (int mi = 0; mi < 4; ++mi) {
      const int n = mi * 16 + lr;
      wf[mi] = *reinterpret_cast<const bf16x8*>(WB + n * 128 + (((ks * 4 + lg) ^ ((n >> 1) & 7)) * 16));
    }
#pragma unroll
    for (int ni = 0; ni < 4; ++ni) {
      const int p = wv * 64 + ni * 16 + lr;
      xf[ni] = *reinterpret_cast<const bf16x8*>(XB + p * 128 + (((ks * 4 + lg) ^ ((p >> 1) & 7)) * 16));
    }
#pragma unroll
    for (int mi = 0; mi < 4; ++mi)
#pragma unroll
      for (int ni = 0; ni < 4; ++ni)
        acc[mi][ni] = __builtin_amdgcn_mfma_f32_16x16x32_bf16(wf[mi], xf[ni], acc[mi][ni], 0, 0, 0);
  }

  // ---- ep1: H = relu(D1 + b1) -> back into Xs (wave-private rows, no barrier) ----
#pragma unroll
  for (int mi = 0; mi < 4; ++mi) {
    const f32x4 bv = *reinterpret_cast<const f32x4*>(&Bs[mi * 16 + lg * 4]);
    const int gH = mi * 2 + (lg >> 1);
    const int offH = (lg & 1) * 8;
#pragma unroll
    for (int ni = 0; ni < 4; ++ni) {
      const int p = wv * 64 + ni * 16 + lr;
      const float h0 = fmaxf(acc[mi][ni][0] + bv[0], 0.f);
      const float h1 = fmaxf(acc[mi][ni][1] + bv[1], 0.f);
      const float h2 = fmaxf(acc[mi][ni][2] + bv[2], 0.f);
      const float h3 = fmaxf(acc[mi][ni][3] + bv[3], 0.f);
      uint2 u; u.x = pack2(h0, h1); u.y = pack2(h2, h3);
      *reinterpret_cast<uint2*>(XB + p * 128 + ((gH ^ ((p >> 1) & 7)) * 16) + offH) = u;
    }
  }

  // ---- layer 2: D2[n][p] = W2t * H^T (wave-private rows) ----
  f32x4 acc2[4][4];
#pragma unroll
  for (int mi = 0; mi < 4; ++mi)
#pragma unroll
    for (int ni = 0; ni < 4; ++ni)
      acc2[mi][ni] = (f32x4){0.f, 0.f, 0.f, 0.f};

#pragma unroll
  for (int ks = 0; ks < 2; ++ks) {
    bf16x8 wf[4], hf[4];
#pragma unroll
    for (int mi = 0; mi < 4; ++mi) {
      const int n = mi * 16 + lr;
      wf[mi] = *reinterpret_cast<const bf16x8*>(WB + 8192 + n * 128 + (((ks * 4 + lg) ^ ((n >> 1) & 7)) * 16));
    }
#pragma unroll
    for (int ni = 0; ni < 4; ++ni) {
      const int p = wv * 64 + ni * 16 + lr;
      hf[ni] = *reinterpret_cast<const bf16x8*>(XB + p * 128 + (((ks * 4 + lg) ^ ((p >> 1) & 7)) * 16));
    }
#pragma unroll
    for (int mi = 0; mi < 4; ++mi)
#pragma unroll
      for (int ni = 0; ni < 4; ++ni)
        acc2[mi][ni] = __builtin_amdgcn_mfma_f32_16x16x32_bf16(wf[mi], hf[ni], acc2[mi][ni], 0, 0, 0);
  }

  // ---- ep2: out = D2 + b2, interleaved (re,im) float2 stores ----
#pragma unroll
  for (int ni = 0; ni < 4; ++ni) {
    const int p = wv * 64 + ni * 16 + lr;
    const int P = p0 + p;
    const int bb = P / 784;
    const int hw = P - bb * 784;
    float* obase = ob + (size_t)bb * 1204224 + hw * 2;
#pragma unroll
    for (int mi = 0; mi < 2; ++mi) {
      const f32x4 bre = *reinterpret_cast<const f32x4*>(&Bs[64 + mi * 16 + lg * 4]);
      const f32x4 bim = *reinterpret_cast<const f32x4*>(&Bs[64 + (mi + 2) * 16 + lg * 4]);
#pragma unroll
      for (int j = 0; j < 4; ++j) {
        const int c = mi * 16 + lg * 4 + j;
        float2 v;
        v.x = acc2[mi][ni][j] + bre[j];
        v.y = acc2[mi + 2][ni][j] + bim[j];
        *reinterpret_cast<float2*>(obase + (size_t)c * 9408) = v;
      }
    }
  }
}

extern "C" void kernel_launch(void* const* d_in, const int* in_sizes, int n_in,
                              void* d_out, int out_size, void* d_ws, size_t ws_size,
                              hipStream_t stream) {
  (void)in_sizes; (void)n_in; (void)out_size; (void)ws_size;
  const float* xl  = (const float*)d_in[0];
  const float* xh  = (const float*)d_in[1];
  const float* wll = (const float*)d_in[2];
  const float* w1  = (const float*)d_in[3];
  const float* w2  = (const float*)d_in[4];
  const float* b1  = (const float*)d_in[5];
  const float* b2  = (const float*)d_in[6];
  float* out = (float*)d_out;
  unsigned short* wg = (unsigned short*)d_ws;   // 65536 bytes used

  prep_weights<<<128, 256, 0, stream>>>(w1, w2, wg);
  fused_kernel<<<6272, 256, 0, stream>>>(xh, wg, b1, b2, xl, wll, out);
}

// Round 4
// 148.671 us; speedup vs baseline: 1.4653x; 1.0186x over previous
//
#include <hip/hip_runtime.h>

typedef __bf16 bf16x8 __attribute__((ext_vector_type(8)));
typedef float  f32x4  __attribute__((ext_vector_type(4)));

// Sizes: B=64, C=128, ORI=6, HW=784, NB=4, BS=32
// xh strides (floats): b:1204224, c:9408, ori:1568, hw:2, ri:1

static __device__ __forceinline__ unsigned short bf16bits(float f) {
  __bf16 h = (__bf16)f; return __builtin_bit_cast(unsigned short, h);
}
static __device__ __forceinline__ unsigned int pack2(float a, float b) {
  return (unsigned int)bf16bits(a) | ((unsigned int)bf16bits(b) << 16);
}

// ---------------- weight prep: combined real matrix, transposed [n][k], bf16,
// written as the PRE-SWIZZLED LDS image so the main kernel does a linear copy.
__global__ void prep_weights(const float* __restrict__ w1, const float* __restrict__ w2,
                             unsigned short* __restrict__ wg) {
  const int e = blockIdx.x * 256 + threadIdx.x;      // 0..32767
  const int nb    = e >> 13;
  const int layer = (e >> 12) & 1;
  const int n = (e >> 6) & 63;
  const int k = e & 63;
  const float* w = layer ? w2 : w1;
  const int kk = k & 31, nn = n & 31;
  float v;
  if (n < 32) {
    v = (k < 32) ?  w[((0 * 4 + nb) * 32 + kk) * 32 + nn]
                 : -w[((1 * 4 + nb) * 32 + kk) * 32 + nn];
  } else {
    v = (k < 32) ?  w[((1 * 4 + nb) * 32 + kk) * 32 + nn]
                 :  w[((0 * 4 + nb) * 32 + kk) * 32 + nn];
  }
  // swizzled position: group g=k>>3 -> g ^ ((n>>1)&7)
  const int pos = nb * 8192 + layer * 4096 + n * 64 + (((k >> 3) ^ ((n >> 1) & 7)) * 8) + (k & 7);
  wg[pos] = bf16bits(v);
}

// ---------------- fused main kernel ----------------
// grid = 6272: (bi&3)==3 -> lowpass block (1568); else xh block (4704):
// xi = (bi>>2)*3+(bi&3); (ori, nb, one 256-position tile)
__global__ __launch_bounds__(256, 3)
void fused_kernel(const float* __restrict__ xh, const unsigned short* __restrict__ wg,
                  const float* __restrict__ b1, const float* __restrict__ b2,
                  const float* __restrict__ xl, const float* __restrict__ wll,
                  float* __restrict__ out) {
  __shared__ __align__(16) unsigned short Xs[256 * 64];   // X tile -> H tile (bf16), 32KB
  __shared__ __align__(16) unsigned short Ws[2 * 64 * 64];// 16KB
  __shared__ __align__(16) float Bs[128];

  const int t = threadIdx.x;
  const int bi = blockIdx.x;

  if ((bi & 3) == 3) {                    // ---- lowpass path: xl_out = xl * w_ll ----
    const int llb = bi >> 2;              // 0..1567, 1024 float4 each
    const float4* xi4 = reinterpret_cast<const float4*>(xl);
    const float4* w4  = reinterpret_cast<const float4*>(wll);
    float4* o4 = reinterpret_cast<float4*>(out);
#pragma unroll
    for (int j = 0; j < 4; ++j) {
      const int i = llb * 1024 + j * 256 + t;
      const float4 x = xi4[i];
      const float4 w = w4[i % 25088];
      float4 r; r.x = x.x * w.x; r.y = x.y * w.y; r.z = x.z * w.z; r.w = x.w * w.w;
      o4[i] = r;
    }
    return;
  }

  const int xi = (bi >> 2) * 3 + (bi & 3);   // 0..4703
  const int mt  = xi % 196;
  const int snb = xi / 196;
  const int ori = snb >> 2;
  const int nb  = snb & 3;
  const int p0 = mt << 8;

  char* XB = reinterpret_cast<char*>(Xs);
  const char* WB = reinterpret_cast<const char*>(Ws);
  const float* xb = xh + (size_t)(nb * 32) * 9408 + ori * 1568;
  float* ob = out + 6422528 + (size_t)(nb * 32) * 9408 + ori * 1568;

  // ================= ISSUE PHASE: all global loads batched, no LDS writes =================
  f32x4 R[16];                               // X tile raw fp32 (64 VGPR)
  uint4 Wr[4];                               // weight image chunks
  float Bv = 0.f;                            // bias element (t<128)

  const int lr16 = t & 15;
  const int cg   = (t >> 4) & 3;
  const int wvi  = t >> 6;
#pragma unroll
  for (int j = 0; j < 8; ++j) {
    const int c = 2 * cg + 8 * (j >> 1);             // even channel of pair
    const int p = 2 * lr16 + 32 * (wvi * 2 + (j & 1)); // even local position
    const int P = p0 + p;
    const int bb = P / 784;
    const int hw = P - bb * 784;
    const float* s = xb + (size_t)bb * 1204224 + c * 9408 + hw * 2;
    R[2 * j]     = *reinterpret_cast<const f32x4*>(s);          // ch c : re,im,re,im
    R[2 * j + 1] = *reinterpret_cast<const f32x4*>(s + 9408);   // ch c+1
  }
  {
    const uint4* src = reinterpret_cast<const uint4*>(wg + nb * 8192);
#pragma unroll
    for (int it = 0; it < 4; ++it) Wr[it] = src[it * 256 + t];
  }
  if (t < 128) {
    const int layer = t >> 6, n = t & 63;
    const float* bsrc = layer ? b2 : b1;
    Bv = bsrc[((n >> 5) * 4 + nb) * 32 + (n & 31)];
  }
  __builtin_amdgcn_sched_barrier(0);         // loads stay ABOVE all LDS writes

  // ================= DRAIN PHASE: convert + LDS writes =================
  {
    uint4* dst = reinterpret_cast<uint4*>(Ws);
#pragma unroll
    for (int it = 0; it < 4; ++it) dst[it * 256 + t] = Wr[it];
  }
  if (t < 128) Bs[t] = Bv;
#pragma unroll
  for (int j = 0; j < 8; ++j) {
    const int c = 2 * cg + 8 * (j >> 1);
    const int p = 2 * lr16 + 32 * (wvi * 2 + (j & 1));
    const int g0 = c >> 3;
    const int off = (c & 7) * 2;
    const int s0 = (p >> 1) & 7;
    const f32x4 vA = R[2 * j], vB = R[2 * j + 1];
    *reinterpret_cast<unsigned int*>(XB + p * 128 + ((g0 ^ s0) * 16) + off)             = pack2(vA[0], vB[0]);
    *reinterpret_cast<unsigned int*>(XB + p * 128 + (((g0 + 4) ^ s0) * 16) + off)       = pack2(vA[1], vB[1]);
    *reinterpret_cast<unsigned int*>(XB + (p + 1) * 128 + ((g0 ^ s0) * 16) + off)       = pack2(vA[2], vB[2]);
    *reinterpret_cast<unsigned int*>(XB + (p + 1) * 128 + (((g0 + 4) ^ s0) * 16) + off) = pack2(vA[3], vB[3]);
  }
  __syncthreads();

  const int lane = t & 63;
  const int wv = t >> 6;
  const int lr = lane & 15;
  const int lg = lane >> 4;

  // ---- layer 1: D1[n][p] = W1t * X^T ----
  f32x4 acc[4][4];
#pragma unroll
  for (int mi = 0; mi < 4; ++mi)
#pragma unroll
    for (int ni = 0; ni < 4; ++ni)
      acc[mi][ni] = (f32x4){0.f, 0.f, 0.f, 0.f};

#pragma unroll
  for (int ks = 0; ks < 2; ++ks) {
    bf16x8 wf[4], xf[4];
#pragma unroll
    for (int mi = 0; mi < 4; ++mi) {
      const int n = mi * 16 + lr;
      wf[mi] = *reinterpret_cast<const bf16x8*>(WB + n * 128 + (((ks * 4 + lg) ^ ((n >> 1) & 7)) * 16));
    }
#pragma unroll
    for (int ni = 0; ni < 4; ++ni) {
      const int p = wv * 64 + ni * 16 + lr;
      xf[ni] = *reinterpret_cast<const bf16x8*>(XB + p * 128 + (((ks * 4 + lg) ^ ((p >> 1) & 7)) * 16));
    }
#pragma unroll
    for (int mi = 0; mi < 4; ++mi)
#pragma unroll
      for (int ni = 0; ni < 4; ++ni)
        acc[mi][ni] = __builtin_amdgcn_mfma_f32_16x16x32_bf16(wf[mi], xf[ni], acc[mi][ni], 0, 0, 0);
  }

  // ---- ep1: H = relu(D1 + b1) -> back into Xs (wave-private rows, no barrier) ----
#pragma unroll
  for (int mi = 0; mi < 4; ++mi) {
    const f32x4 bv = *reinterpret_cast<const f32x4*>(&Bs[mi * 16 + lg * 4]);
    const int gH = mi * 2 + (lg >> 1);
    const int offH = (lg & 1) * 8;
#pragma unroll
    for (int ni = 0; ni < 4; ++ni) {
      const int p = wv * 64 + ni * 16 + lr;
      const float h0 = fmaxf(acc[mi][ni][0] + bv[0], 0.f);
      const float h1 = fmaxf(acc[mi][ni][1] + bv[1], 0.f);
      const float h2 = fmaxf(acc[mi][ni][2] + bv[2], 0.f);
      const float h3 = fmaxf(acc[mi][ni][3] + bv[3], 0.f);
      uint2 u; u.x = pack2(h0, h1); u.y = pack2(h2, h3);
      *reinterpret_cast<uint2*>(XB + p * 128 + ((gH ^ ((p >> 1) & 7)) * 16) + offH) = u;
    }
  }

  // ---- layer 2: D2[n][p] = W2t * H^T (wave-private rows) ----
  f32x4 acc2[4][4];
#pragma unroll
  for (int mi = 0; mi < 4; ++mi)
#pragma unroll
    for (int ni = 0; ni < 4; ++ni)
      acc2[mi][ni] = (f32x4){0.f, 0.f, 0.f, 0.f};

#pragma unroll
  for (int ks = 0; ks < 2; ++ks) {
    bf16x8 wf[4], hf[4];
#pragma unroll
    for (int mi = 0; mi < 4; ++mi) {
      const int n = mi * 16 + lr;
      wf[mi] = *reinterpret_cast<const bf16x8*>(WB + 8192 + n * 128 + (((ks * 4 + lg) ^ ((n >> 1) & 7)) * 16));
    }
#pragma unroll
    for (int ni = 0; ni < 4; ++ni) {
      const int p = wv * 64 + ni * 16 + lr;
      hf[ni] = *reinterpret_cast<const bf16x8*>(XB + p * 128 + (((ks * 4 + lg) ^ ((p >> 1) & 7)) * 16));
    }
#pragma unroll
    for (int mi = 0; mi < 4; ++mi)
#pragma unroll
      for (int ni = 0; ni < 4; ++ni)
        acc2[mi][ni] = __builtin_amdgcn_mfma_f32_16x16x32_bf16(wf[mi], hf[ni], acc2[mi][ni], 0, 0, 0);
  }

  // ---- ep2: out = D2 + b2, interleaved (re,im) float2 stores ----
#pragma unroll
  for (int ni = 0; ni < 4; ++ni) {
    const int p = wv * 64 + ni * 16 + lr;
    const int P = p0 + p;
    const int bb = P / 784;
    const int hw = P - bb * 784;
    float* obase = ob + (size_t)bb * 1204224 + hw * 2;
#pragma unroll
    for (int mi = 0; mi < 2; ++mi) {
      const f32x4 bre = *reinterpret_cast<const f32x4*>(&Bs[64 + mi * 16 + lg * 4]);
      const f32x4 bim = *reinterpret_cast<const f32x4*>(&Bs[64 + (mi + 2) * 16 + lg * 4]);
#pragma unroll
      for (int j = 0; j < 4; ++j) {
        const int c = mi * 16 + lg * 4 + j;
        float2 v;
        v.x = acc2[mi][ni][j] + bre[j];
        v.y = acc2[mi + 2][ni][j] + bim[j];
        *reinterpret_cast<float2*>(obase + (size_t)c * 9408) = v;
      }
    }
  }
}

extern "C" void kernel_launch(void* const* d_in, const int* in_sizes, int n_in,
                              void* d_out, int out_size, void* d_ws, size_t ws_size,
                              hipStream_t stream) {
  (void)in_sizes; (void)n_in; (void)out_size; (void)ws_size;
  const float* xl  = (const float*)d_in[0];
  const float* xh  = (const float*)d_in[1];
  const float* wll = (const float*)d_in[2];
  const float* w1  = (const float*)d_in[3];
  const float* w2  = (const float*)d_in[4];
  const float* b1  = (const float*)d_in[5];
  const float* b2  = (const float*)d_in[6];
  float* out = (float*)d_out;
  unsigned short* wg = (unsigned short*)d_ws;   // 65536 bytes used

  prep_weights<<<128, 256, 0, stream>>>(w1, w2, wg);
  fused_kernel<<<6272, 256, 0, stream>>>(xh, wg, b1, b2, xl, wll, out);
}